// Round 5
// baseline (1524.020 us; speedup 1.0000x reference)
//
#include <hip/hip_runtime.h>
#include <hip/hip_bf16.h>
#include <math.h>

#define HD 1024   // hidden
#define FD 4096   // ffn
#define NE 8      // experts
#define NT 2048   // tokens (B*S)
#define BM 128
#define BN 128
#define BK 32

// ---------------- ws layout (max 144 MiB used; same as R3) ----------------
// counts @0, lists @1024 (64KB), route_w @66560 (16KB), work @82944 (260B)
// xb    @ 1 MiB  : [NT][HD] bf16        (4 MiB)
// hmid  @ 8 MiB  : [2*NT][FD] bf16      (32 MiB)
// wbuf  @ 48 MiB : pass1 W1b/W3b [16][FD][HD] bf16 (128 MiB); pass2 W2b [8][HD][FD] (64 MiB)
// opair @112 MiB : [2][2*NT][HD] f32    (32 MiB)
#define WS_LISTS   1024
#define WS_ROUTEW  (1024 + NE*NT*4)
#define WS_WORK    (WS_ROUTEW + NT*2*4)
#define WS_XB      ((size_t)1 << 20)
#define WS_HMID    ((size_t)8 << 20)
#define WS_WBUF    ((size_t)48 << 20)
#define WS_OPAIR   ((size_t)112 << 20)

typedef __attribute__((ext_vector_type(8))) short bf16x8;   // MFMA A/B frag (4 VGPRs)
typedef __attribute__((ext_vector_type(4))) float f32x4;    // MFMA C/D frag

static __device__ __forceinline__ unsigned int pk_bf16(float a, float b) {
    __hip_bfloat162 h = __float22bfloat162_rn(make_float2(a, b));
    return *reinterpret_cast<unsigned int*>(&h);
}

// async 16B/lane global->LDS. LDS dest = l + lane*16 (wave-uniform l required).
static __device__ __forceinline__ void gll16(const void* g, void* l) {
    __builtin_amdgcn_global_load_lds(
        (const __attribute__((address_space(1))) unsigned int*)g,
        (__attribute__((address_space(3))) unsigned int*)l,
        16, 0, 0);
}

__global__ void prep_kernel(const float* __restrict__ x, unsigned short* __restrict__ xb,
                            int* __restrict__ counts) {
    int idx = blockIdx.x * 256 + threadIdx.x;   // 524288 threads: 4 floats each
    if (idx < NE) counts[idx] = 0;
    float4 v = *(const float4*)(x + (size_t)idx * 4);
    *(uint2*)(xb + (size_t)idx * 4) = make_uint2(pk_bf16(v.x, v.y), pk_bf16(v.z, v.w));
}

__global__ __launch_bounds__(128)
void router_kernel(const float* __restrict__ x, const float* __restrict__ Wr,
                   int* __restrict__ counts, int* __restrict__ lists,
                   float* __restrict__ route_w) {
    int t = blockIdx.x;
    int tid = threadIdx.x;
    float acc[NE];
#pragma unroll
    for (int e = 0; e < NE; e++) acc[e] = 0.f;
    const float* xt = x + (size_t)t * HD;
    for (int h = tid; h < HD; h += 128) {
        float xv = xt[h];
#pragma unroll
        for (int e = 0; e < NE; e++) acc[e] += xv * Wr[e * HD + h];
    }
    __shared__ float red[NE][128];
#pragma unroll
    for (int e = 0; e < NE; e++) red[e][tid] = acc[e];
    __syncthreads();
    for (int s = 64; s > 0; s >>= 1) {
        if (tid < s) {
#pragma unroll
            for (int e = 0; e < NE; e++) red[e][tid] += red[e][tid + s];
        }
        __syncthreads();
    }
    if (tid == 0) {
        int i0 = 0; float l0 = red[0][0];
        for (int e = 1; e < NE; e++) { float v = red[e][0]; if (v > l0) { l0 = v; i0 = e; } }
        int i1 = -1; float l1 = -3.0e38f;
        for (int e = 0; e < NE; e++) {
            if (e == i0) continue;
            float v = red[e][0]; if (v > l1) { l1 = v; i1 = e; }
        }
        float w0 = 1.f / (1.f + expf(l1 - l0));
        float w1 = 1.f - w0;
        int s0 = atomicAdd(&counts[i0], 1);
        lists[i0 * NT + s0] = t * 2;
        route_w[t * 2] = w0;
        int s1 = atomicAdd(&counts[i1], 1);
        lists[i1 * NT + s1] = t * 2 + 1;
        route_w[t * 2 + 1] = w1;
    }
}

// Dense work list: work[i] = (e<<20)|m0 for every needed m-tile; -1 sentinel.
__global__ void plan_kernel(const int* __restrict__ counts, int* __restrict__ work) {
    if (threadIdx.x == 0) {
        int c = 0;
        for (int e = 0; e < NE; e++) {
            int cnt = counts[e];
            for (int m0 = 0; m0 < cnt; m0 += BM) work[c++] = (e << 20) | m0;
        }
        for (int i = c; i < 64; i++) work[i] = -1;
    }
}

// Transpose+convert: src fp32 [R][C] -> dst bf16 [C][R]. z selects slice.
__global__ __launch_bounds__(256)
void transp_kernel(const float* __restrict__ srcA, const float* __restrict__ srcB,
                   unsigned short* __restrict__ dst, int R, int C) {
    __shared__ float tile[64][65];
    int z = blockIdx.z;
    const float* src = (z < 8) ? (srcA + (size_t)z * R * C) : (srcB + (size_t)(z - 8) * R * C);
    unsigned short* d = dst + (size_t)z * R * C;
    int c0 = blockIdx.x * 64, r0 = blockIdx.y * 64;
    int t = threadIdx.x;
    int rr = t >> 4, cc = (t & 15) * 4;
#pragma unroll
    for (int i = 0; i < 4; i++) {
        int r = rr + i * 16;
        float4 v = *(const float4*)(src + (size_t)(r0 + r) * C + c0 + cc);
        tile[cc + 0][r] = v.x; tile[cc + 1][r] = v.y;
        tile[cc + 2][r] = v.z; tile[cc + 3][r] = v.w;
    }
    __syncthreads();
    int cl = t >> 2, rc = (t & 3) * 16;
    unsigned int o[8];
#pragma unroll
    for (int i = 0; i < 8; i++)
        o[i] = pk_bf16(tile[cl][rc + 2 * i], tile[cl][rc + 2 * i + 1]);
    unsigned short* dp = d + (size_t)(c0 + cl) * R + r0 + rc;
    *(uint4*)(dp)     = make_uint4(o[0], o[1], o[2], o[3]);
    *(uint4*)(dp + 8) = make_uint4(o[4], o[5], o[6], o[7]);
}

// GEMM1: gathered xb rows @ W1b/W3b ([n][k] bf16), SwiGLU -> hmid bf16.
// Compact grid (x=nblk 32, y=work idx). XOR chunk-swizzle kills frag-read bank conflicts.
__global__ __launch_bounds__(256, 4)
void gemm1_kernel(const unsigned short* __restrict__ xb, const unsigned short* __restrict__ wbuf,
                  const int* __restrict__ counts, const int* __restrict__ lists,
                  const int* __restrict__ work, unsigned short* __restrict__ hmid) {
    int wi = work[blockIdx.y];
    if (wi < 0) return;
    int e = wi >> 20;
    int m0 = wi & 0xFFFFF;
    int cnt = counts[e];
    int n0 = blockIdx.x * BN;
    const unsigned short* W1b = wbuf + (size_t)e * FD * HD;
    const unsigned short* W3b = wbuf + (size_t)(8 + e) * FD * HD;

    __shared__ __align__(16) unsigned short As[128 * 32];
    __shared__ __align__(16) unsigned short B1s[128 * 32];
    __shared__ __align__(16) unsigned short B3s[128 * 32];
    __shared__ int rp_s[128];

    int tid = threadIdx.x;
    if (tid < 128) {
        int m = m0 + tid;
        rp_s[tid] = (m < cnt) ? lists[e * NT + m] : lists[e * NT];
    }
    __syncthreads();

    const int w = tid >> 6;
    const int lane = tid & 63;
    const int srow = lane >> 2;     // 0..15 row within 16-row issue
    const int schunk = lane & 3;    // 16B chunk within 64B row

    const unsigned short *gA[2], *gB1[2], *gB3[2];
    unsigned short *lA[2], *lB1[2], *lB3[2];
#pragma unroll
    for (int q = 0; q < 2; q++) {
        int row = w * 32 + q * 16 + srow;
        int sc = schunk ^ ((row >> 1) & 3);     // swizzled global chunk
        gA[q]  = xb  + (size_t)(rp_s[row] >> 1) * HD + sc * 8;
        gB1[q] = W1b + (size_t)(n0 + row) * HD + sc * 8;
        gB3[q] = W3b + (size_t)(n0 + row) * HD + sc * 8;
        lA[q]  = &As [(w * 32 + q * 16) * 32];
        lB1[q] = &B1s[(w * 32 + q * 16) * 32];
        lB3[q] = &B3s[(w * 32 + q * 16) * 32];
    }

    const int wr = w >> 1, wc = w & 1;
    const int lm = lane & 15, lg = lane >> 4;

    // per-fragment-row swizzled k-slot offsets (shorts)
    int aoff[4], boff[4];
#pragma unroll
    for (int i = 0; i < 4; i++) {
        int ra = wr * 64 + i * 16 + lm;
        aoff[i] = ra * 32 + (lg ^ ((ra >> 1) & 3)) * 8;
        int rb = wc * 64 + i * 16 + lm;
        boff[i] = rb * 32 + (lg ^ ((rb >> 1) & 3)) * 8;
    }

    f32x4 zf = {0.f, 0.f, 0.f, 0.f};
    f32x4 accG[4][4], accU[4][4];
#pragma unroll
    for (int i = 0; i < 4; i++)
#pragma unroll
        for (int j = 0; j < 4; j++) { accG[i][j] = zf; accU[i][j] = zf; }

    for (int h0 = 0; h0 < HD; h0 += BK) {
        __syncthreads();                    // prior frag reads complete
#pragma unroll
        for (int q = 0; q < 2; q++) {
            gll16(gA[q] + h0, lA[q]);
            gll16(gB1[q] + h0, lB1[q]);
            gll16(gB3[q] + h0, lB3[q]);
        }
        __syncthreads();                    // staging complete

        bf16x8 af[4], b1f[4], b3f[4];
#pragma unroll
        for (int i = 0; i < 4; i++)
            af[i] = *(const bf16x8*)&As[aoff[i]];
#pragma unroll
        for (int j = 0; j < 4; j++) {
            b1f[j] = *(const bf16x8*)&B1s[boff[j]];
            b3f[j] = *(const bf16x8*)&B3s[boff[j]];
        }
#pragma unroll
        for (int i = 0; i < 4; i++)
#pragma unroll
            for (int j = 0; j < 4; j++) {
                accG[i][j] = __builtin_amdgcn_mfma_f32_16x16x32_bf16(af[i], b1f[j], accG[i][j], 0, 0, 0);
                accU[i][j] = __builtin_amdgcn_mfma_f32_16x16x32_bf16(af[i], b3f[j], accU[i][j], 0, 0, 0);
            }
    }

    // epilogue: silu(gate)*up -> bf16. C/D: col(n)=lane&15, row(m)=lg*4+reg (validated R2/R3)
#pragma unroll
    for (int i = 0; i < 4; i++) {
#pragma unroll
        for (int r = 0; r < 4; r++) {
            int ml = wr * 64 + i * 16 + lg * 4 + r;
            int m = m0 + ml;
            if (m < cnt) {
                int p = rp_s[ml];
                unsigned short* hrow = hmid + (size_t)p * FD + n0 + wc * 64 + lm;
#pragma unroll
                for (int j = 0; j < 4; j++) {
                    float g = accG[i][j][r];
                    float u = accU[i][j][r];
                    float v = (g / (1.f + expf(-g))) * u;
                    __hip_bfloat16 hb = __float2bfloat16(v);
                    hrow[j * 16] = *reinterpret_cast<unsigned short*>(&hb);
                }
            }
        }
    }
}

// GEMM2: gathered hmid rows @ W2b [n=h][k=f] bf16, split-K=2, plain stores to opair.
__global__ __launch_bounds__(256, 4)
void gemm2_kernel(const unsigned short* __restrict__ hmid, const unsigned short* __restrict__ wbuf,
                  const int* __restrict__ counts, const int* __restrict__ lists,
                  const int* __restrict__ work, float* __restrict__ opair) {
    int yy = blockIdx.y;
    int ks = yy >> 6;
    int wi = work[yy & 63];
    if (wi < 0) return;
    int e = wi >> 20;
    int m0 = wi & 0xFFFFF;
    int cnt = counts[e];
    int n0 = blockIdx.x * BN;
    const unsigned short* W2b = wbuf + (size_t)e * HD * FD;

    __shared__ __align__(16) unsigned short As[128 * 32];
    __shared__ __align__(16) unsigned short Bs[128 * 32];
    __shared__ int rp_s[128];

    int tid = threadIdx.x;
    if (tid < 128) {
        int m = m0 + tid;
        rp_s[tid] = (m < cnt) ? lists[e * NT + m] : lists[e * NT];
    }
    __syncthreads();

    const int w = tid >> 6;
    const int lane = tid & 63;
    const int srow = lane >> 2;
    const int schunk = lane & 3;

    const unsigned short *gA[2], *gB[2];
    unsigned short *lA[2], *lB[2];
#pragma unroll
    for (int q = 0; q < 2; q++) {
        int row = w * 32 + q * 16 + srow;
        int sc = schunk ^ ((row >> 1) & 3);
        gA[q] = hmid + (size_t)rp_s[row] * FD + sc * 8;
        gB[q] = W2b + (size_t)(n0 + row) * FD + sc * 8;
        lA[q] = &As[(w * 32 + q * 16) * 32];
        lB[q] = &Bs[(w * 32 + q * 16) * 32];
    }

    const int wr = w >> 1, wc = w & 1;
    const int lm = lane & 15, lg = lane >> 4;

    int aoff[4], boff[4];
#pragma unroll
    for (int i = 0; i < 4; i++) {
        int ra = wr * 64 + i * 16 + lm;
        aoff[i] = ra * 32 + (lg ^ ((ra >> 1) & 3)) * 8;
        int rb = wc * 64 + i * 16 + lm;
        boff[i] = rb * 32 + (lg ^ ((rb >> 1) & 3)) * 8;
    }

    f32x4 zf = {0.f, 0.f, 0.f, 0.f};
    f32x4 acc[4][4];
#pragma unroll
    for (int i = 0; i < 4; i++)
#pragma unroll
        for (int j = 0; j < 4; j++) acc[i][j] = zf;

    const int f_begin = ks * (FD / 2);
    const int f_end = f_begin + FD / 2;
    for (int f0 = f_begin; f0 < f_end; f0 += BK) {
        __syncthreads();
#pragma unroll
        for (int q = 0; q < 2; q++) {
            gll16(gA[q] + f0, lA[q]);
            gll16(gB[q] + f0, lB[q]);
        }
        __syncthreads();

        bf16x8 af[4], bf[4];
#pragma unroll
        for (int i = 0; i < 4; i++)
            af[i] = *(const bf16x8*)&As[aoff[i]];
#pragma unroll
        for (int j = 0; j < 4; j++)
            bf[j] = *(const bf16x8*)&Bs[boff[j]];
#pragma unroll
        for (int i = 0; i < 4; i++)
#pragma unroll
            for (int j = 0; j < 4; j++)
                acc[i][j] = __builtin_amdgcn_mfma_f32_16x16x32_bf16(af[i], bf[j], acc[i][j], 0, 0, 0);
    }

#pragma unroll
    for (int i = 0; i < 4; i++) {
#pragma unroll
        for (int r = 0; r < 4; r++) {
            int ml = wr * 64 + i * 16 + lg * 4 + r;
            int m = m0 + ml;
            if (m < cnt) {
                int p = rp_s[ml];
                float* op = opair + ((size_t)ks * (2 * NT) + p) * HD + n0 + wc * 64 + lm;
#pragma unroll
                for (int j = 0; j < 4; j++) op[j * 16] = acc[i][j][r];
            }
        }
    }
}

// out[tok] = w0*(o_ks0[2t]+o_ks1[2t]) + w1*(o_ks0[2t+1]+o_ks1[2t+1])
__global__ __launch_bounds__(256)
void combine_kernel(const float* __restrict__ opair, const float* __restrict__ route_w,
                    float* __restrict__ out) {
    int idx = blockIdx.x * 256 + threadIdx.x;   // 524288
    int tok = idx >> 8;
    int hc = (idx & 255) * 4;
    const float* o0 = opair;
    const float* o1 = opair + (size_t)(2 * NT) * HD;
    size_t r0 = (size_t)(2 * tok) * HD + hc;
    size_t r1 = (size_t)(2 * tok + 1) * HD + hc;
    float w0 = route_w[2 * tok], w1 = route_w[2 * tok + 1];
    float4 a = *(const float4*)(o0 + r0);
    float4 b = *(const float4*)(o1 + r0);
    float4 c = *(const float4*)(o0 + r1);
    float4 d = *(const float4*)(o1 + r1);
    float4 r;
    r.x = w0 * (a.x + b.x) + w1 * (c.x + d.x);
    r.y = w0 * (a.y + b.y) + w1 * (c.y + d.y);
    r.z = w0 * (a.z + b.z) + w1 * (c.z + d.z);
    r.w = w0 * (a.w + b.w) + w1 * (c.w + d.w);
    *(float4*)(out + (size_t)tok * HD + hc) = r;
}

extern "C" void kernel_launch(void* const* d_in, const int* in_sizes, int n_in,
                              void* d_out, int out_size, void* d_ws, size_t ws_size,
                              hipStream_t stream) {
    const float* x  = (const float*)d_in[0];  // [T, H]
    const float* Wr = (const float*)d_in[1];  // [E, H]
    const float* W1 = (const float*)d_in[2];  // [E, H, F]
    const float* W2 = (const float*)d_in[3];  // [E, F, H]
    const float* W3 = (const float*)d_in[4];  // [E, H, F]
    float* out = (float*)d_out;               // [T, H]

    char* ws = (char*)d_ws;
    int*   counts  = (int*)(ws);
    int*   lists   = (int*)(ws + WS_LISTS);
    float* route_w = (float*)(ws + WS_ROUTEW);
    int*   work    = (int*)(ws + WS_WORK);
    unsigned short* xb   = (unsigned short*)(ws + WS_XB);
    unsigned short* hmid = (unsigned short*)(ws + WS_HMID);
    unsigned short* wbuf = (unsigned short*)(ws + WS_WBUF);
    float* opair = (float*)(ws + WS_OPAIR);

    hipLaunchKernelGGL(prep_kernel, dim3(2048), dim3(256), 0, stream, x, xb, counts);
    hipLaunchKernelGGL(router_kernel, dim3(NT), dim3(128), 0, stream,
                       x, Wr, counts, lists, route_w);
    hipLaunchKernelGGL(plan_kernel, dim3(1), dim3(64), 0, stream, counts, work);
    // W1,W3 [H][F] -> wbuf [16][F][H] bf16
    hipLaunchKernelGGL(transp_kernel, dim3(FD / 64, HD / 64, 16), dim3(256), 0, stream,
                       W1, W3, wbuf, HD, FD);
    hipLaunchKernelGGL(gemm1_kernel, dim3(FD / BN, 64), dim3(256), 0, stream,
                       xb, wbuf, counts, lists, work, hmid);
    // W2 [F][H] -> wbuf [8][H][F] bf16 (overwrites W1b region; gemm1 done)
    hipLaunchKernelGGL(transp_kernel, dim3(HD / 64, FD / 64, 8), dim3(256), 0, stream,
                       W2, W2, wbuf, FD, HD);
    hipLaunchKernelGGL(gemm2_kernel, dim3(HD / BN, 128), dim3(256), 0, stream,
                       hmid, wbuf, counts, lists, work, opair);
    hipLaunchKernelGGL(combine_kernel, dim3(2048), dim3(256), 0, stream,
                       opair, route_w, out);
}

// Round 6
// 668.771 us; speedup vs baseline: 2.2788x; 2.2788x over previous
//
#include <hip/hip_runtime.h>
#include <hip/hip_bf16.h>
#include <math.h>

#define HD 1024   // hidden
#define FD 4096   // ffn
#define NE 8      // experts
#define NT 2048   // tokens (B*S)
#define BM 128
#define BN 128
#define BK 32

// ---------------- ws layout (max 144 MiB used; same as R3) ----------------
// counts @0, lists @1024 (64KB), route_w @66560 (16KB), work @82944 (260B)
// xb    @ 1 MiB  : [NT][HD] bf16        (4 MiB)
// hmid  @ 8 MiB  : [2*NT][FD] bf16      (32 MiB)
// wbuf  @ 48 MiB : pass1 W1b/W3b [16][FD][HD] bf16 (128 MiB); pass2 W2b [8][HD][FD] (64 MiB)
// opair @112 MiB : [2][2*NT][HD] f32    (32 MiB)
#define WS_LISTS   1024
#define WS_ROUTEW  (1024 + NE*NT*4)
#define WS_WORK    (WS_ROUTEW + NT*2*4)
#define WS_XB      ((size_t)1 << 20)
#define WS_HMID    ((size_t)8 << 20)
#define WS_WBUF    ((size_t)48 << 20)
#define WS_OPAIR   ((size_t)112 << 20)

typedef __attribute__((ext_vector_type(8))) short bf16x8;   // MFMA A/B frag (4 VGPRs)
typedef __attribute__((ext_vector_type(4))) float f32x4;    // MFMA C/D frag

static __device__ __forceinline__ unsigned int pk_bf16(float a, float b) {
    __hip_bfloat162 h = __float22bfloat162_rn(make_float2(a, b));
    return *reinterpret_cast<unsigned int*>(&h);
}

// async 16B/lane global->LDS. LDS dest = l + lane*16 (wave-uniform l required).
static __device__ __forceinline__ void gll16(const void* g, void* l) {
    __builtin_amdgcn_global_load_lds(
        (const __attribute__((address_space(1))) unsigned int*)g,
        (__attribute__((address_space(3))) unsigned int*)l,
        16, 0, 0);
}

__global__ void prep_kernel(const float* __restrict__ x, unsigned short* __restrict__ xb,
                            int* __restrict__ counts) {
    int idx = blockIdx.x * 256 + threadIdx.x;   // 524288 threads: 4 floats each
    if (idx < NE) counts[idx] = 0;
    float4 v = *(const float4*)(x + (size_t)idx * 4);
    *(uint2*)(xb + (size_t)idx * 4) = make_uint2(pk_bf16(v.x, v.y), pk_bf16(v.z, v.w));
}

__global__ __launch_bounds__(128)
void router_kernel(const float* __restrict__ x, const float* __restrict__ Wr,
                   int* __restrict__ counts, int* __restrict__ lists,
                   float* __restrict__ route_w) {
    int t = blockIdx.x;
    int tid = threadIdx.x;
    float acc[NE];
#pragma unroll
    for (int e = 0; e < NE; e++) acc[e] = 0.f;
    const float* xt = x + (size_t)t * HD;
    for (int h = tid; h < HD; h += 128) {
        float xv = xt[h];
#pragma unroll
        for (int e = 0; e < NE; e++) acc[e] += xv * Wr[e * HD + h];
    }
    __shared__ float red[NE][128];
#pragma unroll
    for (int e = 0; e < NE; e++) red[e][tid] = acc[e];
    __syncthreads();
    for (int s = 64; s > 0; s >>= 1) {
        if (tid < s) {
#pragma unroll
            for (int e = 0; e < NE; e++) red[e][tid] += red[e][tid + s];
        }
        __syncthreads();
    }
    if (tid == 0) {
        int i0 = 0; float l0 = red[0][0];
        for (int e = 1; e < NE; e++) { float v = red[e][0]; if (v > l0) { l0 = v; i0 = e; } }
        int i1 = -1; float l1 = -3.0e38f;
        for (int e = 0; e < NE; e++) {
            if (e == i0) continue;
            float v = red[e][0]; if (v > l1) { l1 = v; i1 = e; }
        }
        float w0 = 1.f / (1.f + expf(l1 - l0));
        float w1 = 1.f - w0;
        int s0 = atomicAdd(&counts[i0], 1);
        lists[i0 * NT + s0] = t * 2;
        route_w[t * 2] = w0;
        int s1 = atomicAdd(&counts[i1], 1);
        lists[i1 * NT + s1] = t * 2 + 1;
        route_w[t * 2 + 1] = w1;
    }
}

// Dense work list: work[i] = (e<<20)|m0 for every needed m-tile; -1 sentinel.
__global__ void plan_kernel(const int* __restrict__ counts, int* __restrict__ work) {
    if (threadIdx.x == 0) {
        int c = 0;
        for (int e = 0; e < NE; e++) {
            int cnt = counts[e];
            for (int m0 = 0; m0 < cnt; m0 += BM) work[c++] = (e << 20) | m0;
        }
        for (int i = c; i < 64; i++) work[i] = -1;
    }
}

// Transpose+convert: src fp32 [R][C] -> dst bf16 [C][R]. z selects slice.
__global__ __launch_bounds__(256)
void transp_kernel(const float* __restrict__ srcA, const float* __restrict__ srcB,
                   unsigned short* __restrict__ dst, int R, int C) {
    __shared__ float tile[64][65];
    int z = blockIdx.z;
    const float* src = (z < 8) ? (srcA + (size_t)z * R * C) : (srcB + (size_t)(z - 8) * R * C);
    unsigned short* d = dst + (size_t)z * R * C;
    int c0 = blockIdx.x * 64, r0 = blockIdx.y * 64;
    int t = threadIdx.x;
    int rr = t >> 4, cc = (t & 15) * 4;
#pragma unroll
    for (int i = 0; i < 4; i++) {
        int r = rr + i * 16;
        float4 v = *(const float4*)(src + (size_t)(r0 + r) * C + c0 + cc);
        tile[cc + 0][r] = v.x; tile[cc + 1][r] = v.y;
        tile[cc + 2][r] = v.z; tile[cc + 3][r] = v.w;
    }
    __syncthreads();
    int cl = t >> 2, rc = (t & 3) * 16;
    unsigned int o[8];
#pragma unroll
    for (int i = 0; i < 8; i++)
        o[i] = pk_bf16(tile[cl][rc + 2 * i], tile[cl][rc + 2 * i + 1]);
    unsigned short* dp = d + (size_t)(c0 + cl) * R + r0 + rc;
    *(uint4*)(dp)     = make_uint4(o[0], o[1], o[2], o[3]);
    *(uint4*)(dp + 8) = make_uint4(o[4], o[5], o[6], o[7]);
}

// GEMM1: gathered xb rows @ W1b/W3b ([n][k] bf16), SwiGLU -> hmid bf16.
// Compact grid (x=nblk 32, y=work idx). XOR chunk-swizzle (R5-verified: conflicts=0).
// launch_bounds(256,2): R5's (256,4) forced VGPR=64 -> scratch-spill catastrophe. Never again.
__global__ __launch_bounds__(256, 2)
void gemm1_kernel(const unsigned short* __restrict__ xb, const unsigned short* __restrict__ wbuf,
                  const int* __restrict__ counts, const int* __restrict__ lists,
                  const int* __restrict__ work, unsigned short* __restrict__ hmid) {
    int wi = work[blockIdx.y];
    if (wi < 0) return;
    int e = wi >> 20;
    int m0 = wi & 0xFFFFF;
    int cnt = counts[e];
    int n0 = blockIdx.x * BN;
    const unsigned short* W1b = wbuf + (size_t)e * FD * HD;
    const unsigned short* W3b = wbuf + (size_t)(8 + e) * FD * HD;

    __shared__ __align__(16) unsigned short As[128 * 32];
    __shared__ __align__(16) unsigned short B1s[128 * 32];
    __shared__ __align__(16) unsigned short B3s[128 * 32];
    __shared__ int rp_s[128];

    int tid = threadIdx.x;
    if (tid < 128) {
        int m = m0 + tid;
        rp_s[tid] = (m < cnt) ? lists[e * NT + m] : lists[e * NT];
    }
    __syncthreads();

    const int w = tid >> 6;
    const int lane = tid & 63;
    const int srow = lane >> 2;     // 0..15 row within 16-row issue
    const int schunk = lane & 3;    // 16B chunk within 64B row

    const unsigned short *gA[2], *gB1[2], *gB3[2];
    unsigned short *lA[2], *lB1[2], *lB3[2];
#pragma unroll
    for (int q = 0; q < 2; q++) {
        int row = w * 32 + q * 16 + srow;
        int sc = schunk ^ ((row >> 1) & 3);     // swizzled global chunk
        gA[q]  = xb  + (size_t)(rp_s[row] >> 1) * HD + sc * 8;
        gB1[q] = W1b + (size_t)(n0 + row) * HD + sc * 8;
        gB3[q] = W3b + (size_t)(n0 + row) * HD + sc * 8;
        lA[q]  = &As [(w * 32 + q * 16) * 32];
        lB1[q] = &B1s[(w * 32 + q * 16) * 32];
        lB3[q] = &B3s[(w * 32 + q * 16) * 32];
    }

    const int wr = w >> 1, wc = w & 1;
    const int lm = lane & 15, lg = lane >> 4;

    // per-fragment-row swizzled k-slot offsets (shorts)
    int aoff[4], boff[4];
#pragma unroll
    for (int i = 0; i < 4; i++) {
        int ra = wr * 64 + i * 16 + lm;
        aoff[i] = ra * 32 + (lg ^ ((ra >> 1) & 3)) * 8;
        int rb = wc * 64 + i * 16 + lm;
        boff[i] = rb * 32 + (lg ^ ((rb >> 1) & 3)) * 8;
    }

    f32x4 zf = {0.f, 0.f, 0.f, 0.f};
    f32x4 accG[4][4], accU[4][4];
#pragma unroll
    for (int i = 0; i < 4; i++)
#pragma unroll
        for (int j = 0; j < 4; j++) { accG[i][j] = zf; accU[i][j] = zf; }

    for (int h0 = 0; h0 < HD; h0 += BK) {
        __syncthreads();                    // prior frag reads complete
#pragma unroll
        for (int q = 0; q < 2; q++) {
            gll16(gA[q] + h0, lA[q]);
            gll16(gB1[q] + h0, lB1[q]);
            gll16(gB3[q] + h0, lB3[q]);
        }
        __syncthreads();                    // staging complete

        bf16x8 af[4], b1f[4], b3f[4];
#pragma unroll
        for (int i = 0; i < 4; i++)
            af[i] = *(const bf16x8*)&As[aoff[i]];
#pragma unroll
        for (int j = 0; j < 4; j++) {
            b1f[j] = *(const bf16x8*)&B1s[boff[j]];
            b3f[j] = *(const bf16x8*)&B3s[boff[j]];
        }
#pragma unroll
        for (int i = 0; i < 4; i++)
#pragma unroll
            for (int j = 0; j < 4; j++) {
                accG[i][j] = __builtin_amdgcn_mfma_f32_16x16x32_bf16(af[i], b1f[j], accG[i][j], 0, 0, 0);
                accU[i][j] = __builtin_amdgcn_mfma_f32_16x16x32_bf16(af[i], b3f[j], accU[i][j], 0, 0, 0);
            }
    }

    // epilogue: silu(gate)*up -> bf16. C/D: col(n)=lane&15, row(m)=lg*4+reg (validated R2/R3/R5)
#pragma unroll
    for (int i = 0; i < 4; i++) {
#pragma unroll
        for (int r = 0; r < 4; r++) {
            int ml = wr * 64 + i * 16 + lg * 4 + r;
            int m = m0 + ml;
            if (m < cnt) {
                int p = rp_s[ml];
                unsigned short* hrow = hmid + (size_t)p * FD + n0 + wc * 64 + lm;
#pragma unroll
                for (int j = 0; j < 4; j++) {
                    float g = accG[i][j][r];
                    float u = accU[i][j][r];
                    float v = (g / (1.f + expf(-g))) * u;
                    __hip_bfloat16 hb = __float2bfloat16(v);
                    hrow[j * 16] = *reinterpret_cast<unsigned short*>(&hb);
                }
            }
        }
    }
}

// GEMM2: gathered hmid rows @ W2b [n=h][k=f] bf16, split-K=2, plain stores to opair.
__global__ __launch_bounds__(256, 2)
void gemm2_kernel(const unsigned short* __restrict__ hmid, const unsigned short* __restrict__ wbuf,
                  const int* __restrict__ counts, const int* __restrict__ lists,
                  const int* __restrict__ work, float* __restrict__ opair) {
    int yy = blockIdx.y;
    int ks = yy >> 6;
    int wi = work[yy & 63];
    if (wi < 0) return;
    int e = wi >> 20;
    int m0 = wi & 0xFFFFF;
    int cnt = counts[e];
    int n0 = blockIdx.x * BN;
    const unsigned short* W2b = wbuf + (size_t)e * HD * FD;

    __shared__ __align__(16) unsigned short As[128 * 32];
    __shared__ __align__(16) unsigned short Bs[128 * 32];
    __shared__ int rp_s[128];

    int tid = threadIdx.x;
    if (tid < 128) {
        int m = m0 + tid;
        rp_s[tid] = (m < cnt) ? lists[e * NT + m] : lists[e * NT];
    }
    __syncthreads();

    const int w = tid >> 6;
    const int lane = tid & 63;
    const int srow = lane >> 2;
    const int schunk = lane & 3;

    const unsigned short *gA[2], *gB[2];
    unsigned short *lA[2], *lB[2];
#pragma unroll
    for (int q = 0; q < 2; q++) {
        int row = w * 32 + q * 16 + srow;
        int sc = schunk ^ ((row >> 1) & 3);
        gA[q] = hmid + (size_t)rp_s[row] * FD + sc * 8;
        gB[q] = W2b + (size_t)(n0 + row) * FD + sc * 8;
        lA[q] = &As[(w * 32 + q * 16) * 32];
        lB[q] = &Bs[(w * 32 + q * 16) * 32];
    }

    const int wr = w >> 1, wc = w & 1;
    const int lm = lane & 15, lg = lane >> 4;

    int aoff[4], boff[4];
#pragma unroll
    for (int i = 0; i < 4; i++) {
        int ra = wr * 64 + i * 16 + lm;
        aoff[i] = ra * 32 + (lg ^ ((ra >> 1) & 3)) * 8;
        int rb = wc * 64 + i * 16 + lm;
        boff[i] = rb * 32 + (lg ^ ((rb >> 1) & 3)) * 8;
    }

    f32x4 zf = {0.f, 0.f, 0.f, 0.f};
    f32x4 acc[4][4];
#pragma unroll
    for (int i = 0; i < 4; i++)
#pragma unroll
        for (int j = 0; j < 4; j++) acc[i][j] = zf;

    const int f_begin = ks * (FD / 2);
    const int f_end = f_begin + FD / 2;
    for (int f0 = f_begin; f0 < f_end; f0 += BK) {
        __syncthreads();
#pragma unroll
        for (int q = 0; q < 2; q++) {
            gll16(gA[q] + f0, lA[q]);
            gll16(gB[q] + f0, lB[q]);
        }
        __syncthreads();

        bf16x8 af[4], bf[4];
#pragma unroll
        for (int i = 0; i < 4; i++)
            af[i] = *(const bf16x8*)&As[aoff[i]];
#pragma unroll
        for (int j = 0; j < 4; j++)
            bf[j] = *(const bf16x8*)&Bs[boff[j]];
#pragma unroll
        for (int i = 0; i < 4; i++)
#pragma unroll
            for (int j = 0; j < 4; j++)
                acc[i][j] = __builtin_amdgcn_mfma_f32_16x16x32_bf16(af[i], bf[j], acc[i][j], 0, 0, 0);
    }

#pragma unroll
    for (int i = 0; i < 4; i++) {
#pragma unroll
        for (int r = 0; r < 4; r++) {
            int ml = wr * 64 + i * 16 + lg * 4 + r;
            int m = m0 + ml;
            if (m < cnt) {
                int p = rp_s[ml];
                float* op = opair + ((size_t)ks * (2 * NT) + p) * HD + n0 + wc * 64 + lm;
#pragma unroll
                for (int j = 0; j < 4; j++) op[j * 16] = acc[i][j][r];
            }
        }
    }
}

// out[tok] = w0*(o_ks0[2t]+o_ks1[2t]) + w1*(o_ks0[2t+1]+o_ks1[2t+1])
__global__ __launch_bounds__(256)
void combine_kernel(const float* __restrict__ opair, const float* __restrict__ route_w,
                    float* __restrict__ out) {
    int idx = blockIdx.x * 256 + threadIdx.x;   // 524288
    int tok = idx >> 8;
    int hc = (idx & 255) * 4;
    const float* o0 = opair;
    const float* o1 = opair + (size_t)(2 * NT) * HD;
    size_t r0 = (size_t)(2 * tok) * HD + hc;
    size_t r1 = (size_t)(2 * tok + 1) * HD + hc;
    float w0 = route_w[2 * tok], w1 = route_w[2 * tok + 1];
    float4 a = *(const float4*)(o0 + r0);
    float4 b = *(const float4*)(o1 + r0);
    float4 c = *(const float4*)(o0 + r1);
    float4 d = *(const float4*)(o1 + r1);
    float4 r;
    r.x = w0 * (a.x + b.x) + w1 * (c.x + d.x);
    r.y = w0 * (a.y + b.y) + w1 * (c.y + d.y);
    r.z = w0 * (a.z + b.z) + w1 * (c.z + d.z);
    r.w = w0 * (a.w + b.w) + w1 * (c.w + d.w);
    *(float4*)(out + (size_t)tok * HD + hc) = r;
}

extern "C" void kernel_launch(void* const* d_in, const int* in_sizes, int n_in,
                              void* d_out, int out_size, void* d_ws, size_t ws_size,
                              hipStream_t stream) {
    const float* x  = (const float*)d_in[0];  // [T, H]
    const float* Wr = (const float*)d_in[1];  // [E, H]
    const float* W1 = (const float*)d_in[2];  // [E, H, F]
    const float* W2 = (const float*)d_in[3];  // [E, F, H]
    const float* W3 = (const float*)d_in[4];  // [E, H, F]
    float* out = (float*)d_out;               // [T, H]

    char* ws = (char*)d_ws;
    int*   counts  = (int*)(ws);
    int*   lists   = (int*)(ws + WS_LISTS);
    float* route_w = (float*)(ws + WS_ROUTEW);
    int*   work    = (int*)(ws + WS_WORK);
    unsigned short* xb   = (unsigned short*)(ws + WS_XB);
    unsigned short* hmid = (unsigned short*)(ws + WS_HMID);
    unsigned short* wbuf = (unsigned short*)(ws + WS_WBUF);
    float* opair = (float*)(ws + WS_OPAIR);

    hipLaunchKernelGGL(prep_kernel, dim3(2048), dim3(256), 0, stream, x, xb, counts);
    hipLaunchKernelGGL(router_kernel, dim3(NT), dim3(128), 0, stream,
                       x, Wr, counts, lists, route_w);
    hipLaunchKernelGGL(plan_kernel, dim3(1), dim3(64), 0, stream, counts, work);
    // W1,W3 [H][F] -> wbuf [16][F][H] bf16
    hipLaunchKernelGGL(transp_kernel, dim3(FD / 64, HD / 64, 16), dim3(256), 0, stream,
                       W1, W3, wbuf, HD, FD);
    hipLaunchKernelGGL(gemm1_kernel, dim3(FD / BN, 64), dim3(256), 0, stream,
                       xb, wbuf, counts, lists, work, hmid);
    // W2 [F][H] -> wbuf [8][H][F] bf16 (overwrites W1b region; gemm1 done)
    hipLaunchKernelGGL(transp_kernel, dim3(HD / 64, FD / 64, 8), dim3(256), 0, stream,
                       W2, W2, wbuf, FD, HD);
    hipLaunchKernelGGL(gemm2_kernel, dim3(HD / BN, 128), dim3(256), 0, stream,
                       hmid, wbuf, counts, lists, work, opair);
    hipLaunchKernelGGL(combine_kernel, dim3(2048), dim3(256), 0, stream,
                       opair, route_w, out);
}